// Round 6
// baseline (488.237 us; speedup 1.0000x reference)
//
#include <hip/hip_runtime.h>
#include <hip/hip_bf16.h>

#define D_IN_C 16
#define BUCKET_SHIFT 9
#define BUCKET_NODES 512           // 1 << BUCKET_SHIFT
#define SRC_SHIFT 15               // src ranges of 32768 nodes = 2MB of h (< 4MB L2/XCD)
#define NSRC 4                     // ceil(100000 / 32768)
#define SUBCAP 6144                // per (bucket,srcrange) capacity: mean 5369 + ~13 sigma
#define PT 16                      // edges per thread in partition kernel
#define PART_CHUNK 4096            // 256 * PT
#define MAXSUB 1024                // >= nbuck*NSRC = 784

// ---------------- Kernel 1: MLP + zero bcur ----------------
__global__ __launch_bounds__(256) void mlp_kernel(
    const float* __restrict__ x,
    const float* __restrict__ w1, const float* __restrict__ b1,
    const float* __restrict__ w2, const float* __restrict__ b2,
    float* __restrict__ h, int* __restrict__ bcur,
    int n_nodes) {
  __shared__ float sw1[256];
  __shared__ float sw2[256];
  __shared__ float sb1[16];
  __shared__ float sb2[16];
  int t = threadIdx.x;
  if (blockIdx.x < MAXSUB / 256) bcur[blockIdx.x * 256 + t] = 0;
  sw1[t] = w1[t];
  sw2[t] = w2[t];
  if (t < 16) { sb1[t] = b1[t]; sb2[t] = b2[t]; }
  __syncthreads();

  int n = blockIdx.x * blockDim.x + t;
  if (n >= n_nodes) return;

  float xi[16];
  const float4* xr = (const float4*)(x + (size_t)n * 16);
  float4 v0 = xr[0], v1 = xr[1], v2 = xr[2], v3 = xr[3];
  xi[0]=v0.x; xi[1]=v0.y; xi[2]=v0.z; xi[3]=v0.w;
  xi[4]=v1.x; xi[5]=v1.y; xi[6]=v1.z; xi[7]=v1.w;
  xi[8]=v2.x; xi[9]=v2.y; xi[10]=v2.z; xi[11]=v2.w;
  xi[12]=v3.x; xi[13]=v3.y; xi[14]=v3.z; xi[15]=v3.w;

  float t1[16];
#pragma unroll
  for (int j = 0; j < 16; ++j) {
    float acc = sb1[j];
#pragma unroll
    for (int k = 0; k < 16; ++k) acc += xi[k] * sw1[k * 16 + j];
    t1[j] = fmaxf(acc, 0.0f);
  }
  float hh[16];
#pragma unroll
  for (int j = 0; j < 16; ++j) {
    float acc = sb2[j];
#pragma unroll
    for (int k = 0; k < 16; ++k) acc += t1[k] * sw2[k * 16 + j];
    hh[j] = acc;
  }

  float4* hw = (float4*)(h + (size_t)n * 16);
  hw[0] = make_float4(hh[0], hh[1], hh[2], hh[3]);
  hw[1] = make_float4(hh[4], hh[5], hh[6], hh[7]);
  hw[2] = make_float4(hh[8], hh[9], hh[10], hh[11]);
  hw[3] = make_float4(hh[12], hh[13], hh[14], hh[15]);
}

// ---------------- Kernel 2: (dst-bucket, src-range) partition ----------------
__global__ __launch_bounds__(256) void part_kernel(
    const int* __restrict__ src, const int* __restrict__ dst,
    int* __restrict__ bcur, int* __restrict__ part,
    int* __restrict__ cnt, int nsub, int nbuck, int n_edges) {
  __shared__ int lhist[MAXSUB];
  __shared__ int lofs[MAXSUB];
  int t = threadIdx.x;
  int base = blockIdx.x * PART_CHUNK;

  // zero the global degree array (consumed by acc_kernel later in the stream)
  int zi = blockIdx.x * 256 + t;
  if (zi < nbuck * BUCKET_NODES) cnt[zi] = 0;

  for (int i = t; i < nsub; i += 256) lhist[i] = 0;
  __syncthreads();

  int d[PT], s[PT];
#pragma unroll
  for (int i = 0; i < PT; ++i) {
    int e = base + i * 256 + t;
    if (e < n_edges) { d[i] = dst[e]; s[i] = src[e]; }
    else d[i] = -1;
  }
#pragma unroll
  for (int i = 0; i < PT; ++i) {
    if (d[i] >= 0) {
      int sb = ((d[i] >> BUCKET_SHIFT) << 2) | (s[i] >> SRC_SHIFT);
      atomicAdd(&lhist[sb], 1);
    }
  }
  __syncthreads();
  for (int i = t; i < nsub; i += 256) {
    int c = lhist[i];
    int r = (c > 0) ? atomicAdd(&bcur[i], c) : 0;
    lofs[i] = i * SUBCAP + r;
  }
  __syncthreads();
#pragma unroll
  for (int i = 0; i < PT; ++i) {
    if (d[i] >= 0) {
      int sb = ((d[i] >> BUCKET_SHIFT) << 2) | (s[i] >> SRC_SHIFT);
      int p = atomicAdd(&lofs[sb], 1);
      part[p] = ((d[i] & (BUCKET_NODES - 1)) << 17) | s[i];
    }
  }
}

// ---------------- Kernel 3: per-(bucket,src-range) LDS accumulation ----------------
// grid = NSRC * nbuck, src-range-major: co-resident blocks gather from the SAME
// 2MB slice of h -> L2-resident gathers (R3/R4/R5 all stalled ~330us on random
// 64B L2-miss fills; FETCH_SIZE 95-106MB vs ~20MB compulsory).
__global__ __launch_bounds__(512, 6) void acc_kernel(
    const float* __restrict__ h, const int* __restrict__ part,
    const int* __restrict__ bcur, int* __restrict__ cnt,
    float* __restrict__ partial,   // NSRC buffers, each nbuck*512*16 floats
    int nbuck) {
  __shared__ float acc[BUCKET_NODES * 16];
  __shared__ int dcnt[BUCKET_NODES];
  int t = threadIdx.x;
  int c = blockIdx.x / nbuck;      // src range (chunk)
  int b = blockIdx.x % nbuck;      // dst bucket

  float4* accz = (float4*)acc;
#pragma unroll
  for (int i = t; i < BUCKET_NODES * 4; i += 512)
    accz[i] = make_float4(0.f, 0.f, 0.f, 0.f);
  dcnt[t] = 0;
  __syncthreads();

  int sub = b * NSRC + c;
  int count = bcur[sub];
  int start = sub * SUBCAP;
  int end = start + count;

  int g = t >> 4;      // 0..31 edge-group
  int k = t & 15;      // feature

  int nfull = count >> 8;   // full 256-edge chunks (32 groups x 8 edges)
  int e = start;
  for (int f = 0; f < nfull; ++f, e += 256) {
    int pk[8];
#pragma unroll
    for (int u = 0; u < 8; ++u) pk[u] = part[e + u * 32 + g];
    float v[8];
#pragma unroll
    for (int u = 0; u < 8; ++u)
      v[u] = h[((unsigned)(pk[u] & 0x1FFFF) << 4) | (unsigned)k];
#pragma unroll
    for (int u = 0; u < 8; ++u) {
      unsigned dl = (unsigned)pk[u] >> 17;
      atomicAdd(&acc[(dl << 4) | (unsigned)k], v[u]);
      if (k == 0) atomicAdd(&dcnt[dl], 1);
    }
  }
  // tail (< 256 edges)
  for (int ee = e + g; ee < end; ee += 32) {
    int pk = part[ee];
    float v = h[((unsigned)(pk & 0x1FFFF) << 4) | (unsigned)k];
    unsigned dl = (unsigned)pk >> 17;
    atomicAdd(&acc[(dl << 4) | (unsigned)k], v);
    if (k == 0) atomicAdd(&dcnt[dl], 1);
  }
  __syncthreads();

  // coalesced flush into this src-range's partial buffer
  float* pout = partial + (size_t)c * nbuck * BUCKET_NODES * 16
                        + (size_t)b * BUCKET_NODES * 16;
  float4* pout4 = (float4*)pout;
  const float4* a4 = (const float4*)acc;
#pragma unroll
  for (int i = t; i < BUCKET_NODES * 4; i += 512) pout4[i] = a4[i];
  int dc = dcnt[t];
  if (dc) atomicAdd(&cnt[b * BUCKET_NODES + t], dc);
}

// ---------------- Kernel 4: reduce partials + SAGE epilogue ----------------
__global__ __launch_bounds__(256) void out_kernel(
    const float* __restrict__ h, const float* __restrict__ partial,
    const int* __restrict__ cnt,
    const float* __restrict__ wl, const float* __restrict__ bl,
    const float* __restrict__ wr, float* __restrict__ out,
    int n_nodes, int nbuck) {
  __shared__ float swl[512];
  __shared__ float swr[512];
  __shared__ float sbl[32];
  int t = threadIdx.x;
  for (int i = t; i < 512; i += 256) { swl[i] = wl[i]; swr[i] = wr[i]; }
  if (t < 32) sbl[t] = bl[t];
  __syncthreads();

  int n = blockIdx.x * 256 + t;
  if (n >= n_nodes) return;

  size_t stride = (size_t)nbuck * BUCKET_NODES * 16;
  float mean[16];
#pragma unroll
  for (int k = 0; k < 16; ++k) mean[k] = 0.0f;
  for (int c = 0; c < NSRC; ++c) {
    const float4* pr = (const float4*)(partial + c * stride + (size_t)n * 16);
    float4 p0 = pr[0], p1 = pr[1], p2 = pr[2], p3 = pr[3];
    mean[0]+=p0.x; mean[1]+=p0.y; mean[2]+=p0.z; mean[3]+=p0.w;
    mean[4]+=p1.x; mean[5]+=p1.y; mean[6]+=p1.z; mean[7]+=p1.w;
    mean[8]+=p2.x; mean[9]+=p2.y; mean[10]+=p2.z; mean[11]+=p2.w;
    mean[12]+=p3.x; mean[13]+=p3.y; mean[14]+=p3.z; mean[15]+=p3.w;
  }
  float inv = 1.0f / fmaxf((float)cnt[n], 1.0f);
#pragma unroll
  for (int k = 0; k < 16; ++k) mean[k] *= inv;

  float hr[16];
  const float4* hp = (const float4*)(h + (size_t)n * 16);
  float4 h0 = hp[0], h1 = hp[1], h2 = hp[2], h3 = hp[3];
  hr[0]=h0.x; hr[1]=h0.y; hr[2]=h0.z; hr[3]=h0.w;
  hr[4]=h1.x; hr[5]=h1.y; hr[6]=h1.z; hr[7]=h1.w;
  hr[8]=h2.x; hr[9]=h2.y; hr[10]=h2.z; hr[11]=h2.w;
  hr[12]=h3.x; hr[13]=h3.y; hr[14]=h3.z; hr[15]=h3.w;

  float o[32];
#pragma unroll
  for (int j = 0; j < 32; ++j) o[j] = sbl[j];
#pragma unroll
  for (int k = 0; k < 16; ++k) {
#pragma unroll
    for (int j = 0; j < 32; ++j) {
      o[j] += mean[k] * swl[k * 32 + j] + hr[k] * swr[k * 32 + j];
    }
  }
  float4* ow = (float4*)(out + (size_t)n * 32);
#pragma unroll
  for (int q = 0; q < 8; ++q)
    ow[q] = make_float4(o[q*4], o[q*4+1], o[q*4+2], o[q*4+3]);
}

extern "C" void kernel_launch(void* const* d_in, const int* in_sizes, int n_in,
                              void* d_out, int out_size, void* d_ws, size_t ws_size,
                              hipStream_t stream) {
  const float* x  = (const float*)d_in[0];
  const int* eidx = (const int*)d_in[1];
  const float* w1 = (const float*)d_in[2];
  const float* b1 = (const float*)d_in[3];
  const float* w2 = (const float*)d_in[4];
  const float* b2 = (const float*)d_in[5];
  const float* wl = (const float*)d_in[6];
  const float* bl = (const float*)d_in[7];
  const float* wr = (const float*)d_in[8];
  float* out = (float*)d_out;

  const int n_nodes = in_sizes[0] / D_IN_C;   // 100000
  const int n_edges = in_sizes[1] / 2;        // 3200000
  const int* src = eidx;
  const int* dst = eidx + n_edges;

  const int nbuck = (n_nodes + BUCKET_NODES - 1) / BUCKET_NODES;  // 196
  const int nsub = nbuck * NSRC;                                  // 784

  // workspace layout (all offsets 16B-aligned)
  float* h     = (float*)d_ws;                          // n_nodes*16 f32
  int* part    = (int*)(h + (size_t)n_nodes * 16);      // nsub*SUBCAP ints (19.3MB)
  int* bcur    = part + (size_t)nsub * SUBCAP;          // MAXSUB ints
  int* cnt     = bcur + MAXSUB;                         // nbuck*512 ints
  float* partial = (float*)(cnt + (size_t)nbuck * BUCKET_NODES);  // NSRC copies

  mlp_kernel<<<(n_nodes + 255) / 256, 256, 0, stream>>>(
      x, w1, b1, w2, b2, h, bcur, n_nodes);
  part_kernel<<<(n_edges + PART_CHUNK - 1) / PART_CHUNK, 256, 0, stream>>>(
      src, dst, bcur, part, cnt, nsub, nbuck, n_edges);
  acc_kernel<<<NSRC * nbuck, 512, 0, stream>>>(
      h, part, bcur, cnt, partial, nbuck);
  out_kernel<<<(n_nodes + 255) / 256, 256, 0, stream>>>(
      h, partial, cnt, wl, bl, wr, out, n_nodes, nbuck);
}